// Round 1
// baseline (740.631 us; speedup 1.0000x reference)
//
#include <hip/hip_runtime.h>

// Problem constants (from reference): T=512, NL=10000, NM=5000, RANK=32, NNZ=10M
#define T_DIM 512
#define RANK 32

// Workspace layout (floats):
//   [0..31]   colsum(Ws)
//   [32..63]  colsum(Ul)
//   [64..95]  colsum(Um)
//   [96]      ll_sum accumulator (sum_n vals*log(clip(A_sum)))
// Zeroed via hipMemsetAsync each launch (ws is re-poisoned 0xAA by harness).

__global__ void colsum_kernel(const float* __restrict__ M, int nrows,
                              float* __restrict__ out) {
    __shared__ float sm[256];
    const int tid = threadIdx.x;
    const int c = tid & 31;        // column
    const int g = tid >> 5;        // row-group 0..7
    float p = 0.f;
    for (int r = blockIdx.x * 8 + g; r < nrows; r += gridDim.x * 8)
        p += M[r * RANK + c];
    sm[tid] = p;
    __syncthreads();
    if (tid < 128) sm[tid] += sm[tid + 128];
    __syncthreads();
    if (tid < 64) sm[tid] += sm[tid + 64];
    __syncthreads();
    if (tid < 32) {
        float v = sm[tid] + sm[tid + 32];
        atomicAdd(out + c, v);
    }
}

__global__ void nnz_kernel(const float* __restrict__ Ws, const float* __restrict__ Ul,
                           const float* __restrict__ Um, const float* __restrict__ vals,
                           const int* __restrict__ s0, const int* __restrict__ s1,
                           const int* __restrict__ s2, float* __restrict__ acc,
                           int nnz) {
    const int tid = blockIdx.x * blockDim.x + threadIdx.x;
    const int stride = gridDim.x * blockDim.x;
    float local = 0.f;
    for (int n = tid; n < nnz; n += stride) {
        const int i = s0[n];
        const int j = s1[n];
        const int k = s2[n];
        const float4* __restrict__ wr = (const float4*)(Ws + i * RANK);
        const float4* __restrict__ ur = (const float4*)(Ul + j * RANK);
        const float4* __restrict__ mr = (const float4*)(Um + k * RANK);
        float s = 0.f;
#pragma unroll
        for (int q = 0; q < 8; ++q) {
            const float4 a = wr[q];
            const float4 b = ur[q];
            const float4 c = mr[q];
            s = fmaf(a.x * b.x, c.x, s);
            s = fmaf(a.y * b.y, c.y, s);
            s = fmaf(a.z * b.z, c.z, s);
            s = fmaf(a.w * b.w, c.w, s);
        }
        s = fmaxf(s, 1e-10f);  // jnp.clip(A_sum, 1e-10)
        local = fmaf(vals[n], __logf(s), local);
    }
    // wave (64-lane) shuffle reduce
#pragma unroll
    for (int off = 32; off > 0; off >>= 1)
        local += __shfl_down(local, off, 64);
    __shared__ float wsum[4];  // 256 threads / 64 lanes
    const int lane = threadIdx.x & 63;
    const int wid = threadIdx.x >> 6;
    if (lane == 0) wsum[wid] = local;
    __syncthreads();
    if (threadIdx.x == 0) {
        atomicAdd(acc, wsum[0] + wsum[1] + wsum[2] + wsum[3]);
    }
}

__global__ void finalize_kernel(const float* __restrict__ w, float* __restrict__ out) {
    const int lane = threadIdx.x;  // one wave of 64
    float p = 0.f;
    if (lane < 32) p = w[lane] * w[32 + lane] * w[64 + lane];
#pragma unroll
    for (int off = 16; off > 0; off >>= 1)
        p += __shfl_down(p, off, 64);
    if (lane == 0) {
        // ll = (ll_sum - sum_M) / T ; return -ll
        out[0] = (p - w[96]) / (float)T_DIM;
    }
}

extern "C" void kernel_launch(void* const* d_in, const int* in_sizes, int n_in,
                              void* d_out, int out_size, void* d_ws, size_t ws_size,
                              hipStream_t stream) {
    const float* Ws   = (const float*)d_in[0];  // [512, 32]
    const float* Ul   = (const float*)d_in[1];  // [10000, 32]
    const float* Um   = (const float*)d_in[2];  // [5000, 32]
    const float* vals = (const float*)d_in[3];  // [NNZ]
    const int*   s0   = (const int*)d_in[4];
    const int*   s1   = (const int*)d_in[5];
    const int*   s2   = (const int*)d_in[6];
    float* out = (float*)d_out;
    float* w   = (float*)d_ws;
    const int nnz = in_sizes[3];
    const int nWs = in_sizes[0] / RANK;   // 512
    const int nUl = in_sizes[1] / RANK;   // 10000
    const int nUm = in_sizes[2] / RANK;   // 5000

    hipMemsetAsync(d_ws, 0, 128 * sizeof(float), stream);

    colsum_kernel<<<64, 256, 0, stream>>>(Ws, nWs, w);
    colsum_kernel<<<256, 256, 0, stream>>>(Ul, nUl, w + 32);
    colsum_kernel<<<128, 256, 0, stream>>>(Um, nUm, w + 64);

    nnz_kernel<<<4096, 256, 0, stream>>>(Ws, Ul, Um, vals, s0, s1, s2, w + 96, nnz);

    finalize_kernel<<<1, 64, 0, stream>>>(w, out);
}

// Round 2
// 421.836 us; speedup vs baseline: 1.7557x; 1.7557x over previous
//
#include <hip/hip_runtime.h>

// CP tensor log-likelihood. T=512, NL=10000, NM=5000, RANK=32, NNZ=10M.
//
// Bottleneck analysis (R1): L1/coalescer request-rate bound. One-thread-per-nnz
// row gathers put 64 distinct rows in every vector load -> ~24 cacheline
// lookups/nnz, ~0.63 lookups/cyc/CU (the L1 tag rate). Fix: 8 lanes per nnz so
// each gather instruction's addresses are contiguous per 8-lane group
// (16 lines/instr instead of 64) -> ~6 lookups/nnz.
//
// Workspace (floats): [0..31] colsum(Ws), [32..63] colsum(Ul),
// [64..95] colsum(Um), [96] ll accumulator.

#define T_DIM 512
#define RANK 32

__global__ void colsum_all_kernel(const float* __restrict__ Ws, int nWs,
                                  const float* __restrict__ Ul, int nUl,
                                  const float* __restrict__ Um, int nUm,
                                  float* __restrict__ w) {
    // blocks 0..15 -> Ws, 16..127 -> Ul, 128..191 -> Um
    const float* M;
    float* out;
    int nrows, b0, nb;
    if (blockIdx.x < 16)       { M = Ws; nrows = nWs; b0 = 0;   nb = 16;  out = w;      }
    else if (blockIdx.x < 128) { M = Ul; nrows = nUl; b0 = 16;  nb = 112; out = w + 32; }
    else                       { M = Um; nrows = nUm; b0 = 128; nb = 64;  out = w + 64; }

    __shared__ float sm[256];
    const int tid = threadIdx.x;
    const int c = tid & 31;        // column
    const int g = tid >> 5;        // row-group 0..7
    float p = 0.f;
    for (int r = (blockIdx.x - b0) * 8 + g; r < nrows; r += nb * 8)
        p += M[r * RANK + c];
    sm[tid] = p;
    __syncthreads();
    if (tid < 128) sm[tid] += sm[tid + 128];
    __syncthreads();
    if (tid < 64) sm[tid] += sm[tid + 64];
    __syncthreads();
    if (tid < 32) atomicAdd(out + c, sm[tid] + sm[tid + 32]);
}

__global__ void nnz_kernel(const float* __restrict__ Ws, const float* __restrict__ Ul,
                           const float* __restrict__ Um, const float* __restrict__ vals,
                           const int* __restrict__ s0, const int* __restrict__ s1,
                           const int* __restrict__ s2, float* __restrict__ acc,
                           int nnz) {
    const int tid = blockIdx.x * blockDim.x + threadIdx.x;
    const int q = tid & 7;                      // quad within row: floats [4q, 4q+3]
    const int gid = tid >> 3;                   // group id -> nnz index
    const int ngroups = (gridDim.x * blockDim.x) >> 3;

    float local = 0.f;
    for (int n = gid; n < nnz; n += ngroups) {
        const int i = s0[n];                    // broadcast within 8-lane group
        const int j = s1[n];
        const int k = s2[n];
        const float4 a = *(const float4*)(Ws + i * RANK + q * 4);
        const float4 b = *(const float4*)(Ul + j * RANK + q * 4);
        const float4 c = *(const float4*)(Um + k * RANK + q * 4);
        float s = a.x * b.x * c.x;
        s = fmaf(a.y * b.y, c.y, s);
        s = fmaf(a.z * b.z, c.z, s);
        s = fmaf(a.w * b.w, c.w, s);
        // reduce across the 8-lane group
        s += __shfl_xor(s, 1, 64);
        s += __shfl_xor(s, 2, 64);
        s += __shfl_xor(s, 4, 64);
        if (q == 0) {
            local = fmaf(vals[n], __logf(fmaxf(s, 1e-10f)), local);
        }
    }

    // wave (64-lane) shuffle reduce, then block reduce, one atomic per block
#pragma unroll
    for (int off = 32; off > 0; off >>= 1)
        local += __shfl_down(local, off, 64);
    __shared__ float wsum[4];
    const int lane = threadIdx.x & 63;
    const int wid = threadIdx.x >> 6;
    if (lane == 0) wsum[wid] = local;
    __syncthreads();
    if (threadIdx.x == 0)
        atomicAdd(acc, wsum[0] + wsum[1] + wsum[2] + wsum[3]);
}

__global__ void finalize_kernel(const float* __restrict__ w, float* __restrict__ out) {
    const int lane = threadIdx.x;  // one wave of 64
    float p = 0.f;
    if (lane < 32) p = w[lane] * w[32 + lane] * w[64 + lane];
#pragma unroll
    for (int off = 16; off > 0; off >>= 1)
        p += __shfl_down(p, off, 64);
    if (lane == 0)
        out[0] = (p - w[96]) / (float)T_DIM;   // -((ll_sum - sum_M)/T)
}

extern "C" void kernel_launch(void* const* d_in, const int* in_sizes, int n_in,
                              void* d_out, int out_size, void* d_ws, size_t ws_size,
                              hipStream_t stream) {
    const float* Ws   = (const float*)d_in[0];
    const float* Ul   = (const float*)d_in[1];
    const float* Um   = (const float*)d_in[2];
    const float* vals = (const float*)d_in[3];
    const int*   s0   = (const int*)d_in[4];
    const int*   s1   = (const int*)d_in[5];
    const int*   s2   = (const int*)d_in[6];
    float* out = (float*)d_out;
    float* w   = (float*)d_ws;
    const int nnz = in_sizes[3];
    const int nWs = in_sizes[0] / RANK;   // 512
    const int nUl = in_sizes[1] / RANK;   // 10000
    const int nUm = in_sizes[2] / RANK;   // 5000

    hipMemsetAsync(d_ws, 0, 128 * sizeof(float), stream);

    colsum_all_kernel<<<192, 256, 0, stream>>>(Ws, nWs, Ul, nUl, Um, nUm, w);

    nnz_kernel<<<4096, 256, 0, stream>>>(Ws, Ul, Um, vals, s0, s1, s2, w + 96, nnz);

    finalize_kernel<<<1, 64, 0, stream>>>(w, out);
}

// Round 3
// 374.008 us; speedup vs baseline: 1.9803x; 1.1279x over previous
//
#include <hip/hip_runtime.h>

// CP tensor log-likelihood. T=512, NL=10000, NM=5000, RANK=32, NNZ=10M.
//
// R2 post-mortem: latency x concurrency bound (VGPR=16 -> serialized loop,
// only ~3 gathers in flight/wave). R3: unroll x4, vectorized stream loads,
// 12 gathers in flight per wave; no atomics/memset (per-block partials);
// colsum fused into main kernel; 2 launches total.
//
// Workspace (floats):
//   ws[0 .. NBLK)               per-block ll partial sums   (every slot written)
//   ws[NBLK .. NBLK+192*32)     colsum partials, block b -> ws[NBLK + b*32 + c]

#define RANK 32
#define NBLK 4096
#define TPB 256
#define CSBLK 192   // colsum blocks: 16 Ws, 112 Ul, 64 Um
#define CSOFF NBLK

__device__ __forceinline__ float dot3(float4 a, float4 b, float4 c) {
    float s = a.x * b.x * c.x;
    s = fmaf(a.y * b.y, c.y, s);
    s = fmaf(a.z * b.z, c.z, s);
    s = fmaf(a.w * b.w, c.w, s);
    return s;
}

__global__ void __launch_bounds__(TPB)
fused_kernel(const float* __restrict__ Ws, int nWs,
             const float* __restrict__ Ul, int nUl,
             const float* __restrict__ Um, int nUm,
             const float* __restrict__ vals,
             const int* __restrict__ s0, const int* __restrict__ s1,
             const int* __restrict__ s2, int nnz,
             float* __restrict__ ws) {
    const int tid = threadIdx.x;
    const int bid = blockIdx.x;
    __shared__ float sm[TPB];

    // ---- Part 1: column-sum partials (blocks 0..191 only) ----
    if (bid < CSBLK) {
        const float* M;
        int nrows, b0, nb;
        if (bid < 16)       { M = Ws; nrows = nWs; b0 = 0;   nb = 16;  }
        else if (bid < 128) { M = Ul; nrows = nUl; b0 = 16;  nb = 112; }
        else                { M = Um; nrows = nUm; b0 = 128; nb = 64;  }
        const int c = tid & 31;
        const int g = tid >> 5;
        float p = 0.f;
        for (int r = (bid - b0) * 8 + g; r < nrows; r += nb * 8)
            p += M[r * RANK + c];
        sm[tid] = p;
        __syncthreads();
        if (tid < 128) sm[tid] += sm[tid + 128];
        __syncthreads();
        if (tid < 64) sm[tid] += sm[tid + 64];
        __syncthreads();
        if (tid < 32) ws[CSOFF + bid * 32 + tid] = sm[tid] + sm[tid + 32];
        __syncthreads();   // sm reused below
    }

    // ---- Part 2: nnz loop, 8 lanes per nonzero, 4 nonzeros per iteration ----
    const int q = tid & 7;                       // quad in row: floats [4q,4q+3]
    const int qo = q * 4;
    const int gid = (bid * TPB + tid) >> 3;
    const int ngroups = (NBLK * TPB) >> 3;       // 131072
    const int nquads = nnz >> 2;

    float local = 0.f;
    for (int n4 = gid; n4 < nquads; n4 += ngroups) {
        const int n0 = n4 << 2;
        const int4 ia   = *(const int4*)(s0 + n0);
        const int4 ib   = *(const int4*)(s1 + n0);
        const int4 ic   = *(const int4*)(s2 + n0);
        const float4 v4 = *(const float4*)(vals + n0);

        const float4 a0 = *(const float4*)(Ws + ia.x * RANK + qo);
        const float4 b0 = *(const float4*)(Ul + ib.x * RANK + qo);
        const float4 c0 = *(const float4*)(Um + ic.x * RANK + qo);
        const float4 a1 = *(const float4*)(Ws + ia.y * RANK + qo);
        const float4 b1 = *(const float4*)(Ul + ib.y * RANK + qo);
        const float4 c1 = *(const float4*)(Um + ic.y * RANK + qo);
        const float4 a2 = *(const float4*)(Ws + ia.z * RANK + qo);
        const float4 b2 = *(const float4*)(Ul + ib.z * RANK + qo);
        const float4 c2 = *(const float4*)(Um + ic.z * RANK + qo);
        const float4 a3 = *(const float4*)(Ws + ia.w * RANK + qo);
        const float4 b3 = *(const float4*)(Ul + ib.w * RANK + qo);
        const float4 c3 = *(const float4*)(Um + ic.w * RANK + qo);

        float sA = dot3(a0, b0, c0);
        float sB = dot3(a1, b1, c1);
        float sC = dot3(a2, b2, c2);
        float sD = dot3(a3, b3, c3);

        // butterfly across the 8-lane group; every lane ends with all 4 sums
        sA += __shfl_xor(sA, 1, 64); sB += __shfl_xor(sB, 1, 64);
        sC += __shfl_xor(sC, 1, 64); sD += __shfl_xor(sD, 1, 64);
        sA += __shfl_xor(sA, 2, 64); sB += __shfl_xor(sB, 2, 64);
        sC += __shfl_xor(sC, 2, 64); sD += __shfl_xor(sD, 2, 64);
        sA += __shfl_xor(sA, 4, 64); sB += __shfl_xor(sB, 4, 64);
        sC += __shfl_xor(sC, 4, 64); sD += __shfl_xor(sD, 4, 64);

        // lane q (q<4) handles nonzero n0+q: one log instruction per 4 nnz
        const float sv = (q == 0) ? sA : (q == 1) ? sB : (q == 2) ? sC : sD;
        const float vv = (q == 0) ? v4.x : (q == 1) ? v4.y : (q == 2) ? v4.z : v4.w;
        if (q < 4)
            local = fmaf(vv, __logf(fmaxf(sv, 1e-10f)), local);
    }

    // tail (nnz % 4), handled by one lane — negligible
    const int tail = nnz & 3;
    if (tail && bid == 0 && tid == 0) {
        for (int n = nnz - tail; n < nnz; ++n) {
            const int i = s0[n], j = s1[n], k = s2[n];
            float s = 0.f;
            for (int r = 0; r < RANK; ++r)
                s = fmaf(Ws[i * RANK + r] * Ul[j * RANK + r], Um[k * RANK + r], s);
            local = fmaf(vals[n], __logf(fmaxf(s, 1e-10f)), local);
        }
    }

    // block reduction -> ws[bid] (no atomics, no init needed)
#pragma unroll
    for (int off = 32; off > 0; off >>= 1)
        local += __shfl_down(local, off, 64);
    __shared__ float wsum[4];
    const int lane = tid & 63;
    const int wid = tid >> 6;
    if (lane == 0) wsum[wid] = local;
    __syncthreads();
    if (tid == 0)
        ws[bid] = wsum[0] + wsum[1] + wsum[2] + wsum[3];
}

__global__ void finalize_kernel(const float* __restrict__ ws, int nWs,
                                float* __restrict__ out) {
    __shared__ float sm[TPB];
    const int tid = threadIdx.x;
    // reduce per-block ll partials
    float l = 0.f;
    for (int i = tid; i < NBLK; i += TPB) l += ws[i];
    sm[tid] = l;
    __syncthreads();
    if (tid < 128) sm[tid] += sm[tid + 128];
    __syncthreads();
    if (tid < 64) sm[tid] += sm[tid + 64];
    __syncthreads();
    if (tid < 32) sm[tid] += sm[tid + 32];
    __syncthreads();
    if (tid < 32) {
        float ll = sm[tid];
#pragma unroll
        for (int off = 16; off > 0; off >>= 1) ll += __shfl_down(ll, off, 32);
        // combine colsum partials: column = tid
        float pw = 0.f, pu = 0.f, pm = 0.f;
        for (int b = 0; b < 16; ++b)    pw += ws[CSOFF + b * 32 + tid];
        for (int b = 16; b < 128; ++b)  pu += ws[CSOFF + b * 32 + tid];
        for (int b = 128; b < 192; ++b) pm += ws[CSOFF + b * 32 + tid];
        float p = pw * pu * pm;
#pragma unroll
        for (int off = 16; off > 0; off >>= 1) p += __shfl_down(p, off, 32);
        if (tid == 0)
            out[0] = (p - ll) / (float)nWs;   // -((ll_sum - sum_M)/T)
    }
}

extern "C" void kernel_launch(void* const* d_in, const int* in_sizes, int n_in,
                              void* d_out, int out_size, void* d_ws, size_t ws_size,
                              hipStream_t stream) {
    const float* Ws   = (const float*)d_in[0];
    const float* Ul   = (const float*)d_in[1];
    const float* Um   = (const float*)d_in[2];
    const float* vals = (const float*)d_in[3];
    const int*   s0   = (const int*)d_in[4];
    const int*   s1   = (const int*)d_in[5];
    const int*   s2   = (const int*)d_in[6];
    float* out = (float*)d_out;
    float* w   = (float*)d_ws;
    const int nnz = in_sizes[3];
    const int nWs = in_sizes[0] / RANK;   // 512
    const int nUl = in_sizes[1] / RANK;   // 10000
    const int nUm = in_sizes[2] / RANK;   // 5000

    fused_kernel<<<NBLK, TPB, 0, stream>>>(Ws, nWs, Ul, nUl, Um, nUm,
                                           vals, s0, s1, s2, nnz, w);
    finalize_kernel<<<1, TPB, 0, stream>>>(w, nWs, out);
}

// Round 4
// 307.367 us; speedup vs baseline: 2.4096x; 1.2168x over previous
//
#include <hip/hip_runtime.h>

// CP tensor log-likelihood. T=512, NL=10000, NM=5000, RANK=32, NNZ=10M.
//
// R3 post-mortem: L2 request-rate bound (~240 G 64B-req/s; 6.25 req/nnz).
// R4: bf16-compress factor matrices (row = 64B = 1 line), LDS-stage Ws
// (32KB, removes it from the global path) -> 2.25 global req/nnz.
// Numerics: output dominated by fp32-exact sum_M; bf16 error on the ll
// term is ~O(1) vs threshold ~4e6.
//
// ws layout (bytes):
//   [0, 16384)          per-block ll partials (4096 floats)
//   [16384, 40960)      colsum partials (192 blocks x 32 floats)
//   [65536, +32KB)      bf16 Ws   (512*32 ushorts)
//   then bf16 Ul (10000*32), bf16 Um (5000*32)   -- ~1.06 MB total

#define RANK 32
#define TPB 256
#define NBLK 4096
#define CSBLK 192          // colsum blocks: 16 Ws, 112 Ul, 64 Um
#define CVTBLK 256         // convert blocks
#define PREB (CSBLK + CVTBLK)

__device__ __forceinline__ unsigned short bfrne(float f) {
    unsigned int u = __float_as_uint(f);
    u += 0x7FFF + ((u >> 16) & 1);          // round-to-nearest-even
    return (unsigned short)(u >> 16);
}

__device__ __forceinline__ void bf2(unsigned int u, float& lo, float& hi) {
    lo = __uint_as_float(u << 16);
    hi = __uint_as_float(u & 0xFFFF0000u);
}

__device__ __forceinline__ float dot8(uint4 a, uint4 b, uint4 c) {
    float al, ah, bl, bh, cl, ch;
    bf2(a.x, al, ah); bf2(b.x, bl, bh); bf2(c.x, cl, ch);
    float s = al * bl * cl;
    s = fmaf(ah * bh, ch, s);
    bf2(a.y, al, ah); bf2(b.y, bl, bh); bf2(c.y, cl, ch);
    s = fmaf(al * bl, cl, s);
    s = fmaf(ah * bh, ch, s);
    bf2(a.z, al, ah); bf2(b.z, bl, bh); bf2(c.z, cl, ch);
    s = fmaf(al * bl, cl, s);
    s = fmaf(ah * bh, ch, s);
    bf2(a.w, al, ah); bf2(b.w, bl, bh); bf2(c.w, cl, ch);
    s = fmaf(al * bl, cl, s);
    s = fmaf(ah * bh, ch, s);
    return s;
}

// ---- prep: colsum partials (fp32-exact) + bf16 conversion ----
__global__ void __launch_bounds__(TPB)
prep_kernel(const float* __restrict__ Ws, int nWs,
            const float* __restrict__ Ul, int nUl,
            const float* __restrict__ Um, int nUm,
            float* __restrict__ csp,
            unsigned short* __restrict__ Wb, unsigned short* __restrict__ Ub,
            unsigned short* __restrict__ Mb) {
    const int tid = threadIdx.x;
    const int bid = blockIdx.x;
    if (bid < CSBLK) {
        __shared__ float sm[TPB];
        const float* M;
        int nrows, b0, nb;
        if (bid < 16)       { M = Ws; nrows = nWs; b0 = 0;   nb = 16;  }
        else if (bid < 128) { M = Ul; nrows = nUl; b0 = 16;  nb = 112; }
        else                { M = Um; nrows = nUm; b0 = 128; nb = 64;  }
        const int c = tid & 31;
        const int g = tid >> 5;
        float p = 0.f;
        for (int r = (bid - b0) * 8 + g; r < nrows; r += nb * 8)
            p += M[r * RANK + c];
        sm[tid] = p;
        __syncthreads();
        if (tid < 128) sm[tid] += sm[tid + 128];
        __syncthreads();
        if (tid < 64) sm[tid] += sm[tid + 64];
        __syncthreads();
        if (tid < 32) csp[bid * 32 + tid] = sm[tid] + sm[tid + 32];
    } else {
        // bf16 conversion, float4-vectorized
        const int eW = nWs * RANK;              // 16384
        const int eU = nUl * RANK;              // 320000
        const int eM = nUm * RANK;              // 160000
        const int NQ = (eW + eU + eM) >> 2;     // quads
        int t = (bid - CSBLK) * TPB + tid;
        for (int qd = t; qd < NQ; qd += CVTBLK * TPB) {
            const int e = qd << 2;
            const float* src;
            unsigned short* dst;
            int off;
            if (e < eW)            { src = Ws; dst = Wb; off = e; }
            else if (e < eW + eU)  { src = Ul; dst = Ub; off = e - eW; }
            else                   { src = Um; dst = Mb; off = e - eW - eU; }
            const float4 f = *(const float4*)(src + off);
            ushort4 h;
            h.x = bfrne(f.x); h.y = bfrne(f.y); h.z = bfrne(f.z); h.w = bfrne(f.w);
            *(ushort4*)(dst + off) = h;
        }
    }
}

// ---- main: nnz loop. 4 lanes/nnz, 4 nnz per group-iteration, Ws in LDS ----
__global__ void __launch_bounds__(TPB)
nnz_kernel(const unsigned short* __restrict__ Wb,
           const unsigned short* __restrict__ Ub,
           const unsigned short* __restrict__ Mb,
           const float* __restrict__ vals,
           const int* __restrict__ s0, const int* __restrict__ s1,
           const int* __restrict__ s2, int nnz,
           float* __restrict__ llp,
           const float* __restrict__ WsF, const float* __restrict__ UlF,
           const float* __restrict__ UmF) {
    __shared__ uint4 lwsv[2048];                // 32KB: bf16 Ws (512 rows x 64B)
    const int tid = threadIdx.x;
    const int bid = blockIdx.x;

    // stage bf16 Ws into LDS
    {
        const uint4* src = (const uint4*)Wb;
        for (int t = tid; t < 2048; t += TPB) lwsv[t] = src[t];
    }
    __syncthreads();
    const unsigned short* lws = (const unsigned short*)lwsv;

    const int q = tid & 3;                      // lane's 16B slice of the 64B row
    const int qe = q * 8;                       // element offset
    const int gid = (bid * TPB + tid) >> 2;
    const int ngroups = (NBLK * TPB) >> 2;      // 262144
    const int nquads = nnz >> 2;

    float local = 0.f;
    for (int n4 = gid; n4 < nquads; n4 += ngroups) {
        const int n0 = n4 << 2;
        const int4 ia   = *(const int4*)(s0 + n0);
        const int4 ib   = *(const int4*)(s1 + n0);
        const int4 ic   = *(const int4*)(s2 + n0);
        const float4 v4 = *(const float4*)(vals + n0);

        const uint4 bA = *(const uint4*)(Ub + ib.x * RANK + qe);
        const uint4 cA = *(const uint4*)(Mb + ic.x * RANK + qe);
        const uint4 bB = *(const uint4*)(Ub + ib.y * RANK + qe);
        const uint4 cB = *(const uint4*)(Mb + ic.y * RANK + qe);
        const uint4 bC = *(const uint4*)(Ub + ib.z * RANK + qe);
        const uint4 cC = *(const uint4*)(Mb + ic.z * RANK + qe);
        const uint4 bD = *(const uint4*)(Ub + ib.w * RANK + qe);
        const uint4 cD = *(const uint4*)(Mb + ic.w * RANK + qe);
        const uint4 aA = *(const uint4*)(lws + ia.x * RANK + qe);
        const uint4 aB = *(const uint4*)(lws + ia.y * RANK + qe);
        const uint4 aC = *(const uint4*)(lws + ia.z * RANK + qe);
        const uint4 aD = *(const uint4*)(lws + ia.w * RANK + qe);

        float sA = dot8(aA, bA, cA);
        float sB = dot8(aB, bB, cB);
        float sC = dot8(aC, bC, cC);
        float sD = dot8(aD, bD, cD);

        // 4-lane butterfly: every lane ends with the full rank-32 sums
        sA += __shfl_xor(sA, 1, 64); sB += __shfl_xor(sB, 1, 64);
        sC += __shfl_xor(sC, 1, 64); sD += __shfl_xor(sD, 1, 64);
        sA += __shfl_xor(sA, 2, 64); sB += __shfl_xor(sB, 2, 64);
        sC += __shfl_xor(sC, 2, 64); sD += __shfl_xor(sD, 2, 64);

        // lane q handles nonzero n0+q: one log per nnz, all lanes active
        const float sv = (q == 0) ? sA : (q == 1) ? sB : (q == 2) ? sC : sD;
        const float vv = (q == 0) ? v4.x : (q == 1) ? v4.y : (q == 2) ? v4.z : v4.w;
        local = fmaf(vv, __logf(fmaxf(sv, 1e-10f)), local);
    }

    // tail (nnz % 4) in exact fp32 — negligible work
    const int tail = nnz & 3;
    if (tail && bid == 0 && tid == 0) {
        for (int n = nnz - tail; n < nnz; ++n) {
            const int i = s0[n], j = s1[n], k = s2[n];
            float s = 0.f;
            for (int r = 0; r < RANK; ++r)
                s = fmaf(WsF[i * RANK + r] * UlF[j * RANK + r], UmF[k * RANK + r], s);
            local = fmaf(vals[n], __logf(fmaxf(s, 1e-10f)), local);
        }
    }

    // block reduction -> llp[bid]
#pragma unroll
    for (int off = 32; off > 0; off >>= 1)
        local += __shfl_down(local, off, 64);
    __shared__ float wsum[4];
    const int lane = tid & 63;
    const int wid = tid >> 6;
    if (lane == 0) wsum[wid] = local;
    __syncthreads();
    if (tid == 0)
        llp[bid] = wsum[0] + wsum[1] + wsum[2] + wsum[3];
}

__global__ void finalize_kernel(const float* __restrict__ llp,
                                const float* __restrict__ csp,
                                int nWs, float* __restrict__ out) {
    __shared__ float sm[TPB];
    const int tid = threadIdx.x;
    float l = 0.f;
    for (int i = tid; i < NBLK; i += TPB) l += llp[i];
    sm[tid] = l;
    __syncthreads();
    if (tid < 128) sm[tid] += sm[tid + 128];
    __syncthreads();
    if (tid < 64) sm[tid] += sm[tid + 64];
    __syncthreads();
    if (tid < 32) sm[tid] += sm[tid + 32];
    __syncthreads();
    if (tid < 32) {
        float ll = sm[tid];
#pragma unroll
        for (int off = 16; off > 0; off >>= 1) ll += __shfl_down(ll, off, 32);
        float pw = 0.f, pu = 0.f, pm = 0.f;
        for (int b = 0; b < 16; ++b)    pw += csp[b * 32 + tid];
        for (int b = 16; b < 128; ++b)  pu += csp[b * 32 + tid];
        for (int b = 128; b < 192; ++b) pm += csp[b * 32 + tid];
        float p = pw * pu * pm;
#pragma unroll
        for (int off = 16; off > 0; off >>= 1) p += __shfl_down(p, off, 32);
        if (tid == 0)
            out[0] = (p - ll) / (float)nWs;    // -((ll_sum - sum_M)/T)
    }
}

extern "C" void kernel_launch(void* const* d_in, const int* in_sizes, int n_in,
                              void* d_out, int out_size, void* d_ws, size_t ws_size,
                              hipStream_t stream) {
    const float* Ws   = (const float*)d_in[0];
    const float* Ul   = (const float*)d_in[1];
    const float* Um   = (const float*)d_in[2];
    const float* vals = (const float*)d_in[3];
    const int*   s0   = (const int*)d_in[4];
    const int*   s1   = (const int*)d_in[5];
    const int*   s2   = (const int*)d_in[6];
    float* out = (float*)d_out;
    const int nnz = in_sizes[3];
    const int nWs = in_sizes[0] / RANK;   // 512
    const int nUl = in_sizes[1] / RANK;   // 10000
    const int nUm = in_sizes[2] / RANK;   // 5000

    char* wsb = (char*)d_ws;
    float* llp = (float*)wsb;                               // 4096 floats
    float* csp = llp + NBLK;                                // 192*32 floats
    unsigned short* Wb = (unsigned short*)(wsb + 65536);    // bf16 Ws
    unsigned short* Ub = Wb + nWs * RANK;                   // bf16 Ul
    unsigned short* Mb = Ub + nUl * RANK;                   // bf16 Um

    prep_kernel<<<PREB, TPB, 0, stream>>>(Ws, nWs, Ul, nUl, Um, nUm, csp, Wb, Ub, Mb);
    nnz_kernel<<<NBLK, TPB, 0, stream>>>(Wb, Ub, Mb, vals, s0, s1, s2, nnz,
                                         llp, Ws, Ul, Um);
    finalize_kernel<<<1, TPB, 0, stream>>>(llp, csp, nWs, out);
}

// Round 5
// 292.367 us; speedup vs baseline: 2.5332x; 1.0513x over previous
//
#include <hip/hip_runtime.h>

// CP tensor log-likelihood. T=512, NL=10000, NM=5000, RANK=32, NNZ=10M.
//
// R4 post-mortem: latency x occupancy bound. 33KB LDS at TPB=256 -> 4 blk/CU
// = 16 waves/CU (38% occ), VALU 33%, waves stall on L2 gather latency.
// R5: TPB=512 (same 4 blk/CU -> 32 waves/CU), explicit index/val prefetch
// pipeline so gather batch issues unobstructed each iteration.
//
// ws layout (bytes):
//   [0, 8192)           per-block ll partials (2048 floats)
//   [8192, 32768)       colsum partials (192 blocks x 32 floats)
//   [65536, +32KB)      bf16 Ws, then bf16 Ul, bf16 Um (~1.06 MB total)

#define RANK 32
#define TPB 512
#define NBLK 2048
#define PTPB 256           // prep threads
#define CSBLK 192          // colsum blocks: 16 Ws, 112 Ul, 64 Um
#define CVTBLK 256
#define PREB (CSBLK + CVTBLK)

__device__ __forceinline__ unsigned short bfrne(float f) {
    unsigned int u = __float_as_uint(f);
    u += 0x7FFF + ((u >> 16) & 1);
    return (unsigned short)(u >> 16);
}

__device__ __forceinline__ void bf2(unsigned int u, float& lo, float& hi) {
    lo = __uint_as_float(u << 16);
    hi = __uint_as_float(u & 0xFFFF0000u);
}

__device__ __forceinline__ float dot8(uint4 a, uint4 b, uint4 c) {
    float al, ah, bl, bh, cl, ch;
    bf2(a.x, al, ah); bf2(b.x, bl, bh); bf2(c.x, cl, ch);
    float s = al * bl * cl;
    s = fmaf(ah * bh, ch, s);
    bf2(a.y, al, ah); bf2(b.y, bl, bh); bf2(c.y, cl, ch);
    s = fmaf(al * bl, cl, s);
    s = fmaf(ah * bh, ch, s);
    bf2(a.z, al, ah); bf2(b.z, bl, bh); bf2(c.z, cl, ch);
    s = fmaf(al * bl, cl, s);
    s = fmaf(ah * bh, ch, s);
    bf2(a.w, al, ah); bf2(b.w, bl, bh); bf2(c.w, cl, ch);
    s = fmaf(al * bl, cl, s);
    s = fmaf(ah * bh, ch, s);
    return s;
}

// ---- prep: fp32-exact colsum partials + bf16 conversion ----
__global__ void __launch_bounds__(PTPB)
prep_kernel(const float* __restrict__ Ws, int nWs,
            const float* __restrict__ Ul, int nUl,
            const float* __restrict__ Um, int nUm,
            float* __restrict__ csp,
            unsigned short* __restrict__ Wb, unsigned short* __restrict__ Ub,
            unsigned short* __restrict__ Mb) {
    const int tid = threadIdx.x;
    const int bid = blockIdx.x;
    if (bid < CSBLK) {
        __shared__ float sm[PTPB];
        const float* M;
        int nrows, b0, nb;
        if (bid < 16)       { M = Ws; nrows = nWs; b0 = 0;   nb = 16;  }
        else if (bid < 128) { M = Ul; nrows = nUl; b0 = 16;  nb = 112; }
        else                { M = Um; nrows = nUm; b0 = 128; nb = 64;  }
        const int c = tid & 31;
        const int g = tid >> 5;
        float p = 0.f;
        for (int r = (bid - b0) * 8 + g; r < nrows; r += nb * 8)
            p += M[r * RANK + c];
        sm[tid] = p;
        __syncthreads();
        if (tid < 128) sm[tid] += sm[tid + 128];
        __syncthreads();
        if (tid < 64) sm[tid] += sm[tid + 64];
        __syncthreads();
        if (tid < 32) csp[bid * 32 + tid] = sm[tid] + sm[tid + 32];
    } else {
        const int eW = nWs * RANK;
        const int eU = nUl * RANK;
        const int eM = nUm * RANK;
        const int NQ = (eW + eU + eM) >> 2;
        int t = (bid - CSBLK) * PTPB + tid;
        for (int qd = t; qd < NQ; qd += CVTBLK * PTPB) {
            const int e = qd << 2;
            const float* src;
            unsigned short* dst;
            int off;
            if (e < eW)            { src = Ws; dst = Wb; off = e; }
            else if (e < eW + eU)  { src = Ul; dst = Ub; off = e - eW; }
            else                   { src = Um; dst = Mb; off = e - eW - eU; }
            const float4 f = *(const float4*)(src + off);
            ushort4 h;
            h.x = bfrne(f.x); h.y = bfrne(f.y); h.z = bfrne(f.z); h.w = bfrne(f.w);
            *(ushort4*)(dst + off) = h;
        }
    }
}

// ---- main: 4 lanes/nnz, 4 nnz/group-iteration, Ws in LDS, stream prefetch ----
__global__ void __launch_bounds__(TPB)
nnz_kernel(const unsigned short* __restrict__ Wb,
           const unsigned short* __restrict__ Ub,
           const unsigned short* __restrict__ Mb,
           const float* __restrict__ vals,
           const int* __restrict__ s0, const int* __restrict__ s1,
           const int* __restrict__ s2, int nnz,
           float* __restrict__ llp,
           const float* __restrict__ WsF, const float* __restrict__ UlF,
           const float* __restrict__ UmF) {
    __shared__ uint4 lwsv[2048];                // 32KB bf16 Ws (512 rows x 64B)
    const int tid = threadIdx.x;
    const int bid = blockIdx.x;

    {
        const uint4* src = (const uint4*)Wb;
        for (int t = tid; t < 2048; t += TPB) lwsv[t] = src[t];
    }
    __syncthreads();
    const unsigned short* lws = (const unsigned short*)lwsv;

    const int q = tid & 3;
    const int qe = q * 8;
    const int gid = (bid * TPB + tid) >> 2;
    const int ngroups = (NBLK * TPB) >> 2;      // 262144
    const int nquads = nnz >> 2;

    float local = 0.f;

    int n4 = gid;
    int4 ia, ib, ic;
    float4 v4;
    if (n4 < nquads) {
        const int n0 = n4 << 2;
        ia = *(const int4*)(s0 + n0);
        ib = *(const int4*)(s1 + n0);
        ic = *(const int4*)(s2 + n0);
        v4 = *(const float4*)(vals + n0);
    }

    while (n4 < nquads) {
        // issue the 8 global + 4 LDS gathers as one cluster
        const uint4 bA = *(const uint4*)(Ub + ia.x * 0 + ib.x * RANK + qe);
        const uint4 cA = *(const uint4*)(Mb + ic.x * RANK + qe);
        const uint4 bB = *(const uint4*)(Ub + ib.y * RANK + qe);
        const uint4 cB = *(const uint4*)(Mb + ic.y * RANK + qe);
        const uint4 bC = *(const uint4*)(Ub + ib.z * RANK + qe);
        const uint4 cC = *(const uint4*)(Mb + ic.z * RANK + qe);
        const uint4 bD = *(const uint4*)(Ub + ib.w * RANK + qe);
        const uint4 cD = *(const uint4*)(Mb + ic.w * RANK + qe);
        const uint4 aA = *(const uint4*)(lws + ia.x * RANK + qe);
        const uint4 aB = *(const uint4*)(lws + ia.y * RANK + qe);
        const uint4 aC = *(const uint4*)(lws + ia.z * RANK + qe);
        const uint4 aD = *(const uint4*)(lws + ia.w * RANK + qe);

        // prefetch next iteration's streams (latency hidden behind dots)
        const int n4n = n4 + ngroups;
        int4 ia2, ib2, ic2;
        float4 v42;
        if (n4n < nquads) {
            const int n0n = n4n << 2;
            ia2 = *(const int4*)(s0 + n0n);
            ib2 = *(const int4*)(s1 + n0n);
            ic2 = *(const int4*)(s2 + n0n);
            v42 = *(const float4*)(vals + n0n);
        }

        float sA = dot8(aA, bA, cA);
        float sB = dot8(aB, bB, cB);
        float sC = dot8(aC, bC, cC);
        float sD = dot8(aD, bD, cD);

        sA += __shfl_xor(sA, 1, 64); sB += __shfl_xor(sB, 1, 64);
        sC += __shfl_xor(sC, 1, 64); sD += __shfl_xor(sD, 1, 64);
        sA += __shfl_xor(sA, 2, 64); sB += __shfl_xor(sB, 2, 64);
        sC += __shfl_xor(sC, 2, 64); sD += __shfl_xor(sD, 2, 64);

        const float sv = (q == 0) ? sA : (q == 1) ? sB : (q == 2) ? sC : sD;
        const float vv = (q == 0) ? v4.x : (q == 1) ? v4.y : (q == 2) ? v4.z : v4.w;
        local = fmaf(vv, __logf(fmaxf(sv, 1e-10f)), local);

        n4 = n4n;
        ia = ia2; ib = ib2; ic = ic2; v4 = v42;
    }

    // tail (nnz % 4) in exact fp32 — negligible
    const int tail = nnz & 3;
    if (tail && bid == 0 && tid == 0) {
        for (int n = nnz - tail; n < nnz; ++n) {
            const int i = s0[n], j = s1[n], k = s2[n];
            float s = 0.f;
            for (int r = 0; r < RANK; ++r)
                s = fmaf(WsF[i * RANK + r] * UlF[j * RANK + r], UmF[k * RANK + r], s);
            local = fmaf(vals[n], __logf(fmaxf(s, 1e-10f)), local);
        }
    }

    // block reduction -> llp[bid]
#pragma unroll
    for (int off = 32; off > 0; off >>= 1)
        local += __shfl_down(local, off, 64);
    __shared__ float wsum[8];
    const int lane = tid & 63;
    const int wid = tid >> 6;
    if (lane == 0) wsum[wid] = local;
    __syncthreads();
    if (tid == 0) {
        float t = 0.f;
#pragma unroll
        for (int i = 0; i < 8; ++i) t += wsum[i];
        llp[bid] = t;
    }
}

__global__ void finalize_kernel(const float* __restrict__ llp,
                                const float* __restrict__ csp,
                                int nWs, float* __restrict__ out) {
    __shared__ float sm[PTPB];
    const int tid = threadIdx.x;
    float l = 0.f;
    for (int i = tid; i < NBLK; i += PTPB) l += llp[i];
    sm[tid] = l;
    __syncthreads();
    if (tid < 128) sm[tid] += sm[tid + 128];
    __syncthreads();
    if (tid < 64) sm[tid] += sm[tid + 64];
    __syncthreads();
    if (tid < 32) sm[tid] += sm[tid + 32];
    __syncthreads();
    if (tid < 32) {
        float ll = sm[tid];
#pragma unroll
        for (int off = 16; off > 0; off >>= 1) ll += __shfl_down(ll, off, 32);
        float pw = 0.f, pu = 0.f, pm = 0.f;
        for (int b = 0; b < 16; ++b)    pw += csp[b * 32 + tid];
        for (int b = 16; b < 128; ++b)  pu += csp[b * 32 + tid];
        for (int b = 128; b < 192; ++b) pm += csp[b * 32 + tid];
        float p = pw * pu * pm;
#pragma unroll
        for (int off = 16; off > 0; off >>= 1) p += __shfl_down(p, off, 32);
        if (tid == 0)
            out[0] = (p - ll) / (float)nWs;    // -((ll_sum - sum_M)/T)
    }
}

extern "C" void kernel_launch(void* const* d_in, const int* in_sizes, int n_in,
                              void* d_out, int out_size, void* d_ws, size_t ws_size,
                              hipStream_t stream) {
    const float* Ws   = (const float*)d_in[0];
    const float* Ul   = (const float*)d_in[1];
    const float* Um   = (const float*)d_in[2];
    const float* vals = (const float*)d_in[3];
    const int*   s0   = (const int*)d_in[4];
    const int*   s1   = (const int*)d_in[5];
    const int*   s2   = (const int*)d_in[6];
    float* out = (float*)d_out;
    const int nnz = in_sizes[3];
    const int nWs = in_sizes[0] / RANK;   // 512
    const int nUl = in_sizes[1] / RANK;   // 10000
    const int nUm = in_sizes[2] / RANK;   // 5000

    char* wsb = (char*)d_ws;
    float* llp = (float*)wsb;                               // 2048 floats
    float* csp = llp + NBLK;                                // 192*32 floats
    unsigned short* Wb = (unsigned short*)(wsb + 65536);
    unsigned short* Ub = Wb + nWs * RANK;
    unsigned short* Mb = Ub + nUl * RANK;

    prep_kernel<<<PREB, PTPB, 0, stream>>>(Ws, nWs, Ul, nUl, Um, nUm, csp, Wb, Ub, Mb);
    nnz_kernel<<<NBLK, TPB, 0, stream>>>(Wb, Ub, Mb, vals, s0, s1, s2, nnz,
                                         llp, Ws, Ul, Um);
    finalize_kernel<<<1, PTPB, 0, stream>>>(llp, csp, nWs, out);
}